// Round 11
// baseline (448.239 us; speedup 1.0000x reference)
//
#include <hip/hip_runtime.h>
#include <hip/hip_bf16.h>
#include <math.h>

#define N_NODES 100000
#define N_EDGES 1600000
#define F_INN   32
#define F_EE    8
#define HD      64
#define E_SL    (N_EDGES + N_NODES)   // edges + self loops
#define NEG_SLOPE 0.2f
#define NPB 32                        // nodes per block in dense kernels (3125 blocks)
#define LOG2E 1.44269504088896340736f

// dst-range bucketing fused into the edge pass. 250 buckets of 400 nodes.
// 8B records {src|dl<<17, pack}; LDS-sorted per block, flushed wave-contiguous.
#define NBKT 250
#define BKT_W (N_NODES / NBKT)        // 400 nodes per bucket
#define BKT_CAP 7200                  // mean 6400 + 10 sigma — overflow prob ~1e-13
#define ME_UNR 10
#define ME_CHUNK (256 * ME_UNR)       // 2560 edges per block
#define ME_BLOCKS (N_EDGES / ME_CHUNK)   // 625
#define PART_CH (ME_BLOCKS * 4)       // 2500 wave partials
#define SB_THREADS 512
#define SEL_CAP (BKT_CAP + BKT_W)     // 7600
#define DEC_EPB 128                   // decode: 128 edges/block, 8 per 16-lane group

typedef float v2f __attribute__((ext_vector_type(2)));   // -> v_pk_*_f32 on gfx950

// ---------- helpers ----------
__device__ __forceinline__ float waveReduceSum(float v) {
#pragma unroll
    for (int off = 32; off > 0; off >>= 1) v += __shfl_down(v, off, 64);
    return v;
}
__device__ __forceinline__ float bf_lo(uint u) { return __uint_as_float(u << 16); }
__device__ __forceinline__ float bf_hi(uint u) { return __uint_as_float(u & 0xffff0000u); }
__device__ __forceinline__ uint pack_bf2(float a, float b) {
    __hip_bfloat16 ha = __float2bfloat16(a), hb = __float2bfloat16(b);
    unsigned short ua, ub;
    __builtin_memcpy(&ua, &ha, 2); __builtin_memcpy(&ub, &hb, 2);
    return (uint)ua | ((uint)ub << 16);
}

// ---------- K1: merged setup — we_vec (pre-scaled by log2e for the exp2
// rebase: leaky_relu is positively homogeneous so the scale commutes),
// Wc/bc fold, bucket-counter zero ----------
__global__ __launch_bounds__(256) void k_setup(const float* __restrict__ edge_w,
                                               const float* __restrict__ att_edge,
                                               const float* __restrict__ enc_w,
                                               const float* __restrict__ enc_b,
                                               const float* __restrict__ W0,
                                               float* __restrict__ we_vec,
                                               float* __restrict__ Wc, float* __restrict__ bc,
                                               int* __restrict__ bkt_pos) {
    int t = threadIdx.x;
    if (t < 16) {
        int l = t >> 3, k = t & 7;
        const float* We = edge_w + l * F_EE * HD + k * HD;
        const float* ae = att_edge + l * HD;
        float s = 0.0f;
#pragma unroll
        for (int j = 0; j < HD; ++j) s += We[j] * ae[j];
        we_vec[l * 8 + k] = s * LOG2E;
    }
    for (int idx = t; idx < F_INN * HD; idx += 256) {
        int r = idx >> 6, c = idx & 63;
        float s = 0.0f;
#pragma unroll
        for (int k = 0; k < HD; ++k) s += enc_w[r * HD + k] * W0[k * HD + c];
        Wc[idx] = s;
    }
    if (t < HD) {
        float s = 0.0f;
#pragma unroll
        for (int k = 0; k < HD; ++k) s += enc_b[k] * W0[k * HD + t];
        bc[t] = s;
    }
    if (t < NBKT) bkt_pos[t] = 0;
}

// ---------- K2a: fused — mean partials, edge-term compute, LDS-sorted bucket flush ----------
__global__ __launch_bounds__(256) void k_mean_edterm(const float* __restrict__ eattr,
                                                     const int* __restrict__ src,
                                                     const int* __restrict__ dst,
                                                     const float* __restrict__ we_vec,
                                                     float* __restrict__ partials,
                                                     uint* __restrict__ bkt,
                                                     int* __restrict__ bkt_pos) {
    __shared__ float sw[16];
    __shared__ int hist[NBKT];     // count, then LDS cursor, then chunk size
    __shared__ int lstart[256];    // scan array -> exclusive LDS record offsets
    __shared__ int gstart[NBKT];   // reserved global record offsets
    __shared__ uint recs[ME_CHUNK * 2];   // 20 KB staged 8B records
    int t = threadIdx.x;
    if (t < 16) sw[t] = we_vec[t];
    if (t < NBKT) hist[t] = 0;
    __syncthreads();
    float p[8];
#pragma unroll
    for (int k = 0; k < 8; ++k) p[k] = 0.0f;
    int e0 = blockIdx.x * ME_CHUNK;
    int rs[ME_UNR]; uint rp[ME_UNR]; int rb[ME_UNR];   // rb = (bucket<<16)|d_local
#pragma unroll
    for (int u = 0; u < ME_UNR; ++u) {
        int e = e0 + u * 256 + t;
        const float4* row = (const float4*)(eattr + (size_t)e * F_EE);
        float4 r0 = row[0], r1 = row[1];
        p[0] += r0.x; p[1] += r0.y; p[2] += r0.z; p[3] += r0.w;
        p[4] += r1.x; p[5] += r1.y; p[6] += r1.z; p[7] += r1.w;
        float ed0 = r0.x * sw[0] + r0.y * sw[1] + r0.z * sw[2] + r0.w * sw[3]
                  + r1.x * sw[4] + r1.y * sw[5] + r1.z * sw[6] + r1.w * sw[7];
        float ed1 = r0.x * sw[8] + r0.y * sw[9] + r0.z * sw[10] + r0.w * sw[11]
                  + r1.x * sw[12] + r1.y * sw[13] + r1.z * sw[14] + r1.w * sw[15];
        rs[u] = src[e];
        rp[u] = pack_bf2(ed0, ed1);
        int d = dst[e];
        int b = d / BKT_W;
        rb[u] = (b << 16) | (d - b * BKT_W);
        atomicAdd(&hist[b], 1);
    }
    __syncthreads();
    // exclusive scan of per-bucket counts -> LDS chunk offsets
    lstart[t] = (t < NBKT) ? hist[t] : 0;
    __syncthreads();
    for (int off = 1; off < 256; off <<= 1) {
        int x = (t >= off) ? lstart[t - off] : 0;
        __syncthreads();
        lstart[t] += x;
        __syncthreads();
    }
    if (t < NBKT) {
        int v = hist[t];
        gstart[t] = atomicAdd(&bkt_pos[t], v);   // exact reservation, no padding
        lstart[t] -= v;                          // inclusive -> exclusive
        hist[t] = 0;                             // reuse as placement cursor
    }
    __syncthreads();
    // place records bucket-sorted into LDS: 8B record = {src | dl<<17, pack}
#pragma unroll
    for (int u = 0; u < ME_UNR; ++u) {
        int b = rb[u] >> 16, dl = rb[u] & 0xFFFF;
        int l = atomicAdd(&hist[b], 1);
        ((uint2*)recs)[lstart[b] + l] = make_uint2((uint)rs[u] | ((uint)dl << 17), rp[u]);
    }
    __syncthreads();
    // per-bucket wave-contiguous flush
    int w = t >> 6, lane = t & 63;
    uint2* gb2 = (uint2*)bkt;
    for (int b = w; b < NBKT; b += 4) {
        int n = hist[b];
        int ls = lstart[b];
        int gs = gstart[b];
        for (int off = lane; off < n; off += 64)
            if (gs + off < BKT_CAP)
                gb2[(size_t)b * BKT_CAP + gs + off] = ((const uint2*)recs)[ls + off];
    }
#pragma unroll
    for (int k = 0; k < 8; ++k) p[k] = waveReduceSum(p[k]);
    if ((t & 63) == 0) {
        float* dstp = partials + ((size_t)blockIdx.x * 4 + w) * 8;
#pragma unroll
        for (int k = 0; k < 8; ++k) dstp[k] = p[k];
    }
}

// ---------- K2b: merged finalize — mean finish + bucket-count scan ----------
__global__ __launch_bounds__(256) void k_finalize(const float* __restrict__ partials,
                                                  const float* __restrict__ we_vec,
                                                  const int* __restrict__ bkt_pos,
                                                  uint* __restrict__ ltp,
                                                  int* __restrict__ bktbase,
                                                  int* __restrict__ row_ptr) {
    __shared__ float red[256];
    __shared__ float mean8[8];
    __shared__ float lt[2];
    __shared__ int sd[256];
    int t = threadIdx.x;
    // phase 1: edge_attr mean -> loop terms (we_vec already log2e-scaled)
    int k = t & 7;
    int chunk = t >> 3;
    float s = 0.0f;
    for (int i = chunk; i < PART_CH; i += 32) s += partials[(size_t)i * 8 + k];
    red[t] = s;
    __syncthreads();
    if (t < 8) {
        float acc = 0.0f;
#pragma unroll
        for (int c = 0; c < 32; ++c) acc += red[c * 8 + t];
        mean8[t] = acc * (1.0f / N_EDGES);
    }
    __syncthreads();
    if (t < 2) {
        float acc = 0.0f;
#pragma unroll
        for (int kk = 0; kk < 8; ++kk) acc += mean8[kk] * we_vec[t * 8 + kk];
        lt[t] = acc;
    }
    __syncthreads();
    if (t == 0) ltp[0] = pack_bf2(lt[0], lt[1]);
    // phase 2: scan bucket counts -> bucket CSR bases
    int v = (t < NBKT) ? min(bkt_pos[t], BKT_CAP) + BKT_W : 0;
    sd[t] = v;
    __syncthreads();
    for (int off = 1; off < 256; off <<= 1) {
        int x = (t >= off) ? sd[t - off] : 0;
        __syncthreads();
        sd[t] += x;
        __syncthreads();
    }
    if (t < NBKT) bktbase[t] = sd[t] - v;
    if (t == 0) row_ptr[N_NODES] = E_SL;
}

// kB: one block per bucket. Counting-sort the bucket's ~6400 8B records in LDS,
// write row_ptr for its 400 nodes, write agg as fully contiguous stream.
__global__ __launch_bounds__(SB_THREADS) void k_sort_build(const int* __restrict__ bkt_pos,
                                                           const uint* __restrict__ bkt,
                                                           const int* __restrict__ bktbase,
                                                           const uint* __restrict__ ltp,
                                                           int2* __restrict__ agg,
                                                           int* __restrict__ row_ptr) {
    __shared__ int S[BKT_W];                 // inclusive scan of per-node counts
    __shared__ int cur[BKT_W];               // hist, then rank cursor
    __shared__ unsigned short sel[SEL_CAP];  // local position -> record idx | selfloop
    int b = blockIdx.x;
    int t = threadIdx.x;
    int cnt = min(bkt_pos[b], BKT_CAP);
    const uint2* bp = (const uint2*)bkt + (size_t)b * BKT_CAP;
    if (t < BKT_W) cur[t] = 0;
    __syncthreads();
    for (int i = t; i < cnt; i += SB_THREADS) {
        uint2 v = bp[i];                     // streams bucket through L2
        atomicAdd(&cur[v.x >> 17], 1);
    }
    __syncthreads();
    if (t < BKT_W) S[t] = cur[t];
    for (int off = 1; off < BKT_W; off <<= 1) {
        __syncthreads();
        int x = (t >= off && t < BKT_W) ? S[t - off] : 0;
        __syncthreads();
        if (t < BKT_W) S[t] += x;
    }
    __syncthreads();
    int n0 = b * BKT_W;
    int gb = bktbase[b];
    if (t < BKT_W) {
        row_ptr[n0 + t] = gb + (t == 0 ? 0 : S[t - 1]) + t;   // excl scan of (cnt+1)
        cur[t] = 0;
        sel[S[t] + t] = (unsigned short)(0x8000 | t);   // self-loop slot (segment end)
    }
    __syncthreads();
    for (int i = t; i < cnt; i += SB_THREADS) {
        int dl = (int)(bp[i].x >> 17);       // L2 re-read
        int r = atomicAdd(&cur[dl], 1);
        int nb = (dl == 0) ? 0 : S[dl - 1];
        sel[nb + dl + r] = (unsigned short)i;
    }
    __syncthreads();
    int total = cnt + BKT_W;
    uint lt = ltp[0];
    for (int p = t; p < total; p += SB_THREADS) {
        unsigned short v = sel[p];
        int2 a;
        if (v & 0x8000) {
            a = make_int2(n0 + (v & 0x7fff), (int)lt);
        } else {
            uint2 r = bp[v];                 // random read within resident bucket
            a = make_int2((int)(r.x & 0x1FFFFu), (int)r.y);
        }
        agg[gb + p] = a;                     // contiguous coalesced stream
    }
}

// ---------- K3: layer-0 projection xp = x@Wc + bc ----------
__global__ __launch_bounds__(256) void k_xp0(const float* __restrict__ x,
                                             const float* __restrict__ Wc,
                                             const float* __restrict__ bc,
                                             const float* __restrict__ a_src,
                                             const float* __restrict__ a_dst,
                                             __hip_bfloat16* __restrict__ xpb,
                                             float* __restrict__ s_src,
                                             float* __restrict__ s_dst) {
    __shared__ float xr[NPB * F_INN];  // 4 KB
    int t = threadIdx.x;
    int j = t & 63, wv = t >> 6;
    float4 w[F_INN / 4];               // 8 VGPR float4s = weight column j
#pragma unroll
    for (int kk = 0; kk < F_INN / 4; ++kk) {
        w[kk].x = Wc[(4 * kk + 0) * HD + j];
        w[kk].y = Wc[(4 * kk + 1) * HD + j];
        w[kk].z = Wc[(4 * kk + 2) * HD + j];
        w[kk].w = Wc[(4 * kk + 3) * HD + j];
    }
    int n0 = blockIdx.x * NPB;
    ((float4*)xr)[t] = ((const float4*)(x + (size_t)n0 * F_INN))[t];  // 4KB exact
    __syncthreads();
    float asj = a_src[j], adj = a_dst[j], bcj = bc[j];
    for (int n = wv; n < NPB; n += 4) {
        const float4* hx = (const float4*)&xr[n * F_INN];
        float acc = bcj;
#pragma unroll
        for (int kk = 0; kk < F_INN / 4; ++kk) {
            float4 hv = hx[kk];   // wave-uniform broadcast ds_read_b128
            acc += hv.x * w[kk].x + hv.y * w[kk].y + hv.z * w[kk].z + hv.w * w[kk].w;
        }
        int node = n0 + n;
        xpb[(size_t)node * HD + j] = __float2bfloat16(acc);
        float ts = waveReduceSum(acc * asj);
        float td = waveReduceSum(acc * adj);
        if (j == 0) { s_src[node] = ts * LOG2E; s_dst[node] = td * LOG2E; }   // exp2 rebase
    }
}

// ---------- K4: xp(bf16) = h @ W (layer 1) — h bf16 ----------
__global__ __launch_bounds__(256) void k_xp(const unsigned short* __restrict__ hb,
                                            const float* __restrict__ W,
                                            const float* __restrict__ a_src, const float* __restrict__ a_dst,
                                            __hip_bfloat16* __restrict__ xpb, float* __restrict__ s_src,
                                            float* __restrict__ s_dst) {
    __shared__ unsigned short hr[NPB * HD];   // 4 KB bf16 tile
    int t = threadIdx.x;
    int j = t & 63, wv = t >> 6;
    float4 w[HD / 4];                  // 16 float4s = 64 VGPRs
#pragma unroll
    for (int kk = 0; kk < HD / 4; ++kk) {
        w[kk].x = W[(4 * kk + 0) * HD + j];
        w[kk].y = W[(4 * kk + 1) * HD + j];
        w[kk].z = W[(4 * kk + 2) * HD + j];
        w[kk].w = W[(4 * kk + 3) * HD + j];
    }
    int n0 = blockIdx.x * NPB;
    ((uint4*)hr)[t] = ((const uint4*)(hb + (size_t)n0 * HD))[t];   // 4KB exact
    __syncthreads();
    float asj = a_src[j], adj = a_dst[j];
    for (int n = wv; n < NPB; n += 4) {
        const uint2* hx = (const uint2*)&hr[n * HD];
        float acc = 0.0f;
#pragma unroll
        for (int kk = 0; kk < HD / 4; ++kk) {
            uint2 hv = hx[kk];   // broadcast ds_read_b64: 4 bf16
            acc += bf_lo(hv.x) * w[kk].x + bf_hi(hv.x) * w[kk].y
                 + bf_lo(hv.y) * w[kk].z + bf_hi(hv.y) * w[kk].w;
        }
        int node = n0 + n;
        xpb[(size_t)node * HD + j] = __float2bfloat16(acc);
        float ts = waveReduceSum(acc * asj);
        float td = waveReduceSum(acc * adj);
        if (j == 0) { s_src[node] = ts * LOG2E; s_dst[node] = td * LOG2E; }   // exp2 rebase
    }
}

// ---------- K5: gather-aggregate — r9 analysis: latency+VALU plateau (FETCH
// at per-XCD fill floor, HBM 25%, VALU 67%). This round:
//  (1) FULL 1-deep pipeline: records AND xpr rows AND s_src scalars for
//      iteration i+1 issue before iteration i's compute — the ~200cy row-
//      gather latency now overlaps the exp/FMA work instead of following it;
//  (2) exp2 rebase (terms pre-scaled by log2e) — exp2f lowers to native
//      v_exp_f32 (r10 fix: __exp2f is a glibc macro collision, not a builtin);
//  (3) float2 packed accumulate -> v_pk_fma_f32 (half the FMA issue). ----------
template <int LAYER>
__global__ __launch_bounds__(256) void k_aggregate(const int* __restrict__ row_ptr,
                                                   const int2* __restrict__ agg,
                                                   const float* __restrict__ s_src,
                                                   const float* __restrict__ s_dst,
                                                   const uint2* __restrict__ xpr,   // bf16 x4 per lane
                                                   const float* __restrict__ bias,
                                                   unsigned short* __restrict__ hb) {
    int t = threadIdx.x;
    int node = blockIdx.x * 4 + (t >> 6);    // grid exact: N/4
    int lane = t & 63;
    int g = lane >> 4, li = lane & 15;
    int start = row_ptr[node], end = row_ptr[node + 1];
    float sd = s_dst[node];
    v2f axy = {0.0f, 0.0f}, azw = {0.0f, 0.0f};
    float den = 0.0f;
    int i = start;
    if (i + 8 <= end) {
        int2 r0 = agg[i + g];
        int2 r1 = agg[i + 4 + g];
        uint2 u0 = xpr[(uint)(r0.x * 16 + li)];
        uint2 u1 = xpr[(uint)(r1.x * 16 + li)];
        float ss0 = s_src[r0.x], ss1 = s_src[r1.x];
        while (true) {
            int ni = i + 8;
            bool more = ni + 8 <= end;
            int2 nr0, nr1; uint2 nu0, nu1; float ns0 = 0.0f, ns1 = 0.0f;
            if (more) {                      // full next-iteration prefetch
                nr0 = agg[ni + g];
                nr1 = agg[ni + 4 + g];
                nu0 = xpr[(uint)(nr0.x * 16 + li)];
                nu1 = xpr[(uint)(nr1.x * 16 + li)];
                ns0 = s_src[nr0.x];
                ns1 = s_src[nr1.x];
            }
            float a0 = ss0 + sd + (LAYER == 0 ? bf_lo((uint)r0.y) : bf_hi((uint)r0.y));
            float a1 = ss1 + sd + (LAYER == 0 ? bf_lo((uint)r1.y) : bf_hi((uint)r1.y));
            a0 = a0 > 0.0f ? a0 : NEG_SLOPE * a0;
            a1 = a1 > 0.0f ? a1 : NEG_SLOPE * a1;
            float ex0 = exp2f(a0), ex1 = exp2f(a1);
            den += ex0 + ex1;
            v2f e0 = {ex0, ex0}, e1 = {ex1, ex1};
            v2f l0 = {bf_lo(u0.x), bf_hi(u0.x)};
            v2f h0 = {bf_lo(u0.y), bf_hi(u0.y)};
            v2f l1 = {bf_lo(u1.x), bf_hi(u1.x)};
            v2f h1 = {bf_lo(u1.y), bf_hi(u1.y)};
            axy += e0 * l0; axy += e1 * l1;  // v_pk_fma_f32
            azw += e0 * h0; azw += e1 * h1;
            i = ni;
            if (!more) break;
            r0 = nr0; r1 = nr1; u0 = nu0; u1 = nu1; ss0 = ns0; ss1 = ns1;
        }
    }
    if (i < end) {                           // single predicated 8-wide tail pass
        int idx0 = i + g, idx1 = i + 4 + g;
        bool v0 = idx0 < end, v1 = idx1 < end;
        int2 r0 = agg[v0 ? idx0 : start];
        int2 r1 = agg[v1 ? idx1 : start];
        int sp0 = r0.x, sp1 = r1.x;
        uint2 u0 = xpr[(uint)(sp0 * 16 + li)];
        uint2 u1 = xpr[(uint)(sp1 * 16 + li)];
        float a0 = s_src[sp0] + sd + (LAYER == 0 ? bf_lo((uint)r0.y) : bf_hi((uint)r0.y));
        float a1 = s_src[sp1] + sd + (LAYER == 0 ? bf_lo((uint)r1.y) : bf_hi((uint)r1.y));
        a0 = a0 > 0.0f ? a0 : NEG_SLOPE * a0;
        a1 = a1 > 0.0f ? a1 : NEG_SLOPE * a1;
        float ex0 = v0 ? exp2f(a0) : 0.0f;
        float ex1 = v1 ? exp2f(a1) : 0.0f;
        den += ex0 + ex1;
        v2f e0 = {ex0, ex0}, e1 = {ex1, ex1};
        v2f l0 = {bf_lo(u0.x), bf_hi(u0.x)};
        v2f h0 = {bf_lo(u0.y), bf_hi(u0.y)};
        v2f l1 = {bf_lo(u1.x), bf_hi(u1.x)};
        v2f h1 = {bf_lo(u1.y), bf_hi(u1.y)};
        axy += e0 * l0; axy += e1 * l1;
        azw += e0 * h0; azw += e1 * h1;
    }
    float ax = axy.x, ay = axy.y, az = azw.x, aw = azw.y;
    den += __shfl_down(den, 32, 64); ax += __shfl_down(ax, 32, 64);
    ay  += __shfl_down(ay, 32, 64); az += __shfl_down(az, 32, 64);
    aw  += __shfl_down(aw, 32, 64);
    den += __shfl_down(den, 16, 64); ax += __shfl_down(ax, 16, 64);
    ay  += __shfl_down(ay, 16, 64); az += __shfl_down(az, 16, 64);
    aw  += __shfl_down(aw, 16, 64);
    if (lane < 16) {
        float inv = 1.0f / (den + 1e-16f);
        float4 b4 = ((const float4*)bias)[li];
        uint2 hv;
        hv.x = pack_bf2(fmaxf(ax * inv + b4.x, 0.0f), fmaxf(ay * inv + b4.y, 0.0f));
        hv.y = pack_bf2(fmaxf(az * inv + b4.z, 0.0f), fmaxf(aw * inv + b4.w, 0.0f));
        ((uint2*)(hb + (size_t)node * HD))[li] = hv;
    }
}

// ---------- K6: u1(bf16)=h@W1a, u2b(bf16)=h@W1b + b1 — h bf16 ----------
__global__ __launch_bounds__(256) void k_umm(const unsigned short* __restrict__ hb,
                                             const float* __restrict__ w1,
                                             const float* __restrict__ b1,
                                             __hip_bfloat16* __restrict__ u1b,
                                             __hip_bfloat16* __restrict__ u2b) {
    __shared__ unsigned short hr[NPB * HD];   // 4 KB bf16 tile
    int t = threadIdx.x;
    int j = t & 63, wv = t >> 6;
    float4 wa[HD / 4], wb[HD / 4];     // 128 VGPRs
#pragma unroll
    for (int kk = 0; kk < HD / 4; ++kk) {
        wa[kk].x = w1[(4 * kk + 0) * HD + j];
        wa[kk].y = w1[(4 * kk + 1) * HD + j];
        wa[kk].z = w1[(4 * kk + 2) * HD + j];
        wa[kk].w = w1[(4 * kk + 3) * HD + j];
        wb[kk].x = w1[(HD + 4 * kk + 0) * HD + j];
        wb[kk].y = w1[(HD + 4 * kk + 1) * HD + j];
        wb[kk].z = w1[(HD + 4 * kk + 2) * HD + j];
        wb[kk].w = w1[(HD + 4 * kk + 3) * HD + j];
    }
    float b1j = b1[j];
    int n0 = blockIdx.x * NPB;
    ((uint4*)hr)[t] = ((const uint4*)(hb + (size_t)n0 * HD))[t];   // 4KB exact
    __syncthreads();
    for (int n = wv; n < NPB; n += 4) {
        const uint2* hx = (const uint2*)&hr[n * HD];
        float a1 = 0.0f, a2 = 0.0f;
#pragma unroll
        for (int kk = 0; kk < HD / 4; ++kk) {
            uint2 hv = hx[kk];   // broadcast ds_read_b64: 4 bf16
            float h0 = bf_lo(hv.x), h1 = bf_hi(hv.x), h2 = bf_lo(hv.y), h3 = bf_hi(hv.y);
            a1 += h0 * wa[kk].x + h1 * wa[kk].y + h2 * wa[kk].z + h3 * wa[kk].w;
            a2 += h0 * wb[kk].x + h1 * wb[kk].y + h2 * wb[kk].z + h3 * wb[kk].w;
        }
        int node = n0 + n;
        u1b[(size_t)node * HD + j] = __float2bfloat16(a1);
        u2b[(size_t)node * HD + j] = __float2bfloat16(a2 + b1j);
    }
}

// ---------- K7: edge-order decode — 128 edges/block, 8 per 16-lane group =
// 16 independent 128B row-gathers in flight per group. out coalesced. ----------
__global__ __launch_bounds__(256) void k_decode_edge(const int* __restrict__ src,
                                                     const int* __restrict__ dst,
                                                     const uint2* __restrict__ u1r,
                                                     const uint2* __restrict__ u2r,
                                                     const float* __restrict__ w2,
                                                     const float* __restrict__ b2,
                                                     float* __restrict__ out) {
    __shared__ int sld[2 * DEC_EPB];
    int t = threadIdx.x;
    int e0 = blockIdx.x * DEC_EPB;       // grid exact: E/128 blocks
    sld[t] = (t < DEC_EPB) ? src[e0 + t] : dst[e0 + t - DEC_EPB];
    __syncthreads();
    int g = t >> 4, li = t & 15;         // 16 groups of 16 lanes, 8 edges/group
    float4 w4 = ((const float4*)w2)[li];
    float bb = b2[0];
    uint2 u[8], v[8];
#pragma unroll
    for (int k = 0; k < 8; ++k) {        // 16 independent row gathers back-to-back
        int sk = sld[g + 16 * k];
        int dk = sld[DEC_EPB + g + 16 * k];
        u[k] = u1r[(uint)(sk * 16 + li)];
        v[k] = u2r[(uint)(dk * 16 + li)];
    }
    float p[8];
#pragma unroll
    for (int k = 0; k < 8; ++k) {
        p[k] = fmaxf(bf_lo(u[k].x) + bf_lo(v[k].x), 0.0f) * w4.x
             + fmaxf(bf_hi(u[k].x) + bf_hi(v[k].x), 0.0f) * w4.y
             + fmaxf(bf_lo(u[k].y) + bf_lo(v[k].y), 0.0f) * w4.z
             + fmaxf(bf_hi(u[k].y) + bf_hi(v[k].y), 0.0f) * w4.w;
    }
#pragma unroll
    for (int off = 8; off > 0; off >>= 1) {
#pragma unroll
        for (int k = 0; k < 8; ++k) p[k] += __shfl_down(p[k], off, 16);
    }
    if (li == 0) {
#pragma unroll
        for (int k = 0; k < 8; ++k)
            out[e0 + 16 * k + g] = 1.0f / (1.0f + __expf(-(p[k] + bb)));
    }
}

extern "C" void kernel_launch(void* const* d_in, const int* in_sizes, int n_in,
                              void* d_out, int out_size, void* d_ws, size_t ws_size,
                              hipStream_t stream) {
    const float* x        = (const float*)d_in[0];
    const int*   eidx     = (const int*)d_in[1];
    const float* eattr    = (const float*)d_in[2];
    const float* enc_w    = (const float*)d_in[3];
    const float* enc_b    = (const float*)d_in[4];
    const float* gat_w    = (const float*)d_in[5];
    const float* att_src  = (const float*)d_in[6];
    const float* att_dst  = (const float*)d_in[7];
    const float* edge_w   = (const float*)d_in[8];
    const float* att_edge = (const float*)d_in[9];
    const float* gat_b    = (const float*)d_in[10];
    const float* lp_w1    = (const float*)d_in[11];
    const float* lp_b1    = (const float*)d_in[12];
    const float* lp_w2    = (const float*)d_in[13];
    const float* lp_b2    = (const float*)d_in[14];
    float* out = (float*)d_out;

    const int* src = eidx;
    const int* dst = eidx + N_EDGES;

    // ---- workspace layout (bytes) ----
    // [0, 14.4MB):  bkt (8B records; live edterm->sort_build)
    //               hb bf16 N*HD = 12.8MB (live aggregate<0> -> umm) aliases it
    // [14.4, 27.2): xpb bf16 N*HD (u1b after umm)
    // [27.2, 40.8): agg E_SL int2 (u2b bf16 after umm — agg dead post agg<1>)
    // [40.8, ...):  small arrays
    char* wsb = (char*)d_ws;
    uint*   bkt = (uint*)wsb;                               // NBKT*BKT_CAP*8B = 14.4MB
    unsigned short* hb = (unsigned short*)wsb;              // N*HD bf16 (12.8MB)
    __hip_bfloat16* xpb = (__hip_bfloat16*)(wsb + (size_t)NBKT * BKT_CAP * 8);
    int2*   agg = (int2*)((char*)xpb + (size_t)N_NODES * HD * 2);   // 13.6MB
    float*  fsmall    = (float*)(agg + E_SL);
    float*  s_src     = fsmall;                             // N
    float*  s_dst     = s_src + N_NODES;                    // N
    float*  partials  = s_dst + N_NODES;                    // PART_CH*8 (20000)
    float*  we_vec    = partials + PART_CH * 8;             // 16
    uint*   ltp       = (uint*)(we_vec + 16);               // 1
    float*  Wc        = (float*)(ltp + 1);                  // 32*64
    float*  bc        = Wc + F_INN * HD;                    // 64
    int*    row_ptr   = (int*)(bc + HD);                    // N+1
    int*    bkt_pos   = row_ptr + N_NODES + 1;              // NBKT
    int*    bktbase   = bkt_pos + NBKT;                     // NBKT

    const int NB_AGG  = N_NODES / 4;             // 25000
    const int NB_DENSE = N_NODES / NPB;          // 3125
    const int NB_DEC  = N_EDGES / DEC_EPB;       // 12500

    // merged setup (we_vec + Wc/bc + counter zero) then fused edge pass
    k_setup<<<1, 256, 0, stream>>>(edge_w, att_edge, enc_w, enc_b, gat_w,
                                   we_vec, Wc, bc, bkt_pos);
    k_mean_edterm<<<ME_BLOCKS, 256, 0, stream>>>(eattr, src, dst, we_vec,
                                                 partials, bkt, bkt_pos);
    k_finalize<<<1, 256, 0, stream>>>(partials, we_vec, bkt_pos, ltp, bktbase, row_ptr);

    // per-bucket LDS counting sort -> CSR agg records + row_ptr
    k_sort_build<<<NBKT, SB_THREADS, 0, stream>>>(bkt_pos, bkt, bktbase, ltp,
                                                  agg, row_ptr);

    // layer-0 projection (encoder folded into Wc/bc)
    k_xp0<<<NB_DENSE, 256, 0, stream>>>(x, Wc, bc, att_src, att_dst, xpb, s_src, s_dst);
    k_aggregate<0><<<NB_AGG, 256, 0, stream>>>(row_ptr, agg, s_src, s_dst,
                                               (const uint2*)xpb, gat_b, hb);
    // GAT layer 1
    k_xp<<<NB_DENSE, 256, 0, stream>>>(hb, gat_w + HD * HD, att_src + HD, att_dst + HD,
                                       xpb, s_src, s_dst);
    k_aggregate<1><<<NB_AGG, 256, 0, stream>>>(row_ptr, agg, s_src, s_dst,
                                               (const uint2*)xpb, gat_b + HD, hb);

    // decoder: u1b -> xpb buffer, u2b(+b1) -> agg buffer (both dead by now);
    // decode in ORIGINAL edge order (coalesced out)
    k_umm<<<NB_DENSE, 256, 0, stream>>>(hb, lp_w1, lp_b1, xpb,
                                        (__hip_bfloat16*)agg);
    k_decode_edge<<<NB_DEC, 256, 0, stream>>>(src, dst, (const uint2*)xpb,
                                              (const uint2*)agg, lp_w2, lp_b2, out);
}

// Round 12
// 444.927 us; speedup vs baseline: 1.0074x; 1.0074x over previous
//
#include <hip/hip_runtime.h>
#include <hip/hip_bf16.h>
#include <math.h>

#define N_NODES 100000
#define N_EDGES 1600000
#define F_INN   32
#define F_EE    8
#define HD      64
#define E_SL    (N_EDGES + N_NODES)   // edges + self loops
#define NEG_SLOPE 0.2f
#define NPB 32                        // nodes per block in dense kernels (3125 blocks)
#define LOG2E 1.44269504088896340736f

// dst-range bucketing fused into the edge pass. 250 buckets of 400 nodes.
// 8B records {src|dl<<17, pack}; LDS-sorted per block, flushed wave-contiguous.
#define NBKT 250
#define BKT_W (N_NODES / NBKT)        // 400 nodes per bucket
#define BKT_CAP 7200                  // mean 6400 + 10 sigma — overflow prob ~1e-13
#define ME_UNR 10
#define ME_CHUNK (256 * ME_UNR)       // 2560 edges per block
#define ME_BLOCKS (N_EDGES / ME_CHUNK)   // 625
#define PART_CH (ME_BLOCKS * 4)       // 2500 wave partials
#define SB_THREADS 512
#define SEL_CAP (BKT_CAP + BKT_W)     // 7600
#define DEC_EPB 128                   // decode: 128 edges/block, 8 per 16-lane group

// ---------- helpers ----------
__device__ __forceinline__ float waveReduceSum(float v) {
#pragma unroll
    for (int off = 32; off > 0; off >>= 1) v += __shfl_down(v, off, 64);
    return v;
}
__device__ __forceinline__ float bf_lo(uint u) { return __uint_as_float(u << 16); }
__device__ __forceinline__ float bf_hi(uint u) { return __uint_as_float(u & 0xffff0000u); }
__device__ __forceinline__ uint pack_bf2(float a, float b) {
    __hip_bfloat16 ha = __float2bfloat16(a), hb = __float2bfloat16(b);
    unsigned short ua, ub;
    __builtin_memcpy(&ua, &ha, 2); __builtin_memcpy(&ub, &hb, 2);
    return (uint)ua | ((uint)ub << 16);
}

// ---------- K1: merged setup — we_vec (pre-scaled by log2e: leaky_relu is
// positively homogeneous so the scale commutes; exp(x) = exp2(x*log2e) and
// exp2f lowers to the native v_exp_f32), Wc/bc fold, bucket-counter zero ----------
__global__ __launch_bounds__(256) void k_setup(const float* __restrict__ edge_w,
                                               const float* __restrict__ att_edge,
                                               const float* __restrict__ enc_w,
                                               const float* __restrict__ enc_b,
                                               const float* __restrict__ W0,
                                               float* __restrict__ we_vec,
                                               float* __restrict__ Wc, float* __restrict__ bc,
                                               int* __restrict__ bkt_pos) {
    int t = threadIdx.x;
    if (t < 16) {
        int l = t >> 3, k = t & 7;
        const float* We = edge_w + l * F_EE * HD + k * HD;
        const float* ae = att_edge + l * HD;
        float s = 0.0f;
#pragma unroll
        for (int j = 0; j < HD; ++j) s += We[j] * ae[j];
        we_vec[l * 8 + k] = s * LOG2E;
    }
    for (int idx = t; idx < F_INN * HD; idx += 256) {
        int r = idx >> 6, c = idx & 63;
        float s = 0.0f;
#pragma unroll
        for (int k = 0; k < HD; ++k) s += enc_w[r * HD + k] * W0[k * HD + c];
        Wc[idx] = s;
    }
    if (t < HD) {
        float s = 0.0f;
#pragma unroll
        for (int k = 0; k < HD; ++k) s += enc_b[k] * W0[k * HD + t];
        bc[t] = s;
    }
    if (t < NBKT) bkt_pos[t] = 0;
}

// ---------- K2a: fused — mean partials, edge-term compute, LDS-sorted bucket flush ----------
__global__ __launch_bounds__(256) void k_mean_edterm(const float* __restrict__ eattr,
                                                     const int* __restrict__ src,
                                                     const int* __restrict__ dst,
                                                     const float* __restrict__ we_vec,
                                                     float* __restrict__ partials,
                                                     uint* __restrict__ bkt,
                                                     int* __restrict__ bkt_pos) {
    __shared__ float sw[16];
    __shared__ int hist[NBKT];     // count, then LDS cursor, then chunk size
    __shared__ int lstart[256];    // scan array -> exclusive LDS record offsets
    __shared__ int gstart[NBKT];   // reserved global record offsets
    __shared__ uint recs[ME_CHUNK * 2];   // 20 KB staged 8B records
    int t = threadIdx.x;
    if (t < 16) sw[t] = we_vec[t];
    if (t < NBKT) hist[t] = 0;
    __syncthreads();
    float p[8];
#pragma unroll
    for (int k = 0; k < 8; ++k) p[k] = 0.0f;
    int e0 = blockIdx.x * ME_CHUNK;
    int rs[ME_UNR]; uint rp[ME_UNR]; int rb[ME_UNR];   // rb = (bucket<<16)|d_local
#pragma unroll
    for (int u = 0; u < ME_UNR; ++u) {
        int e = e0 + u * 256 + t;
        const float4* row = (const float4*)(eattr + (size_t)e * F_EE);
        float4 r0 = row[0], r1 = row[1];
        p[0] += r0.x; p[1] += r0.y; p[2] += r0.z; p[3] += r0.w;
        p[4] += r1.x; p[5] += r1.y; p[6] += r1.z; p[7] += r1.w;
        float ed0 = r0.x * sw[0] + r0.y * sw[1] + r0.z * sw[2] + r0.w * sw[3]
                  + r1.x * sw[4] + r1.y * sw[5] + r1.z * sw[6] + r1.w * sw[7];
        float ed1 = r0.x * sw[8] + r0.y * sw[9] + r0.z * sw[10] + r0.w * sw[11]
                  + r1.x * sw[12] + r1.y * sw[13] + r1.z * sw[14] + r1.w * sw[15];
        rs[u] = src[e];
        rp[u] = pack_bf2(ed0, ed1);
        int d = dst[e];
        int b = d / BKT_W;
        rb[u] = (b << 16) | (d - b * BKT_W);
        atomicAdd(&hist[b], 1);
    }
    __syncthreads();
    // exclusive scan of per-bucket counts -> LDS chunk offsets
    lstart[t] = (t < NBKT) ? hist[t] : 0;
    __syncthreads();
    for (int off = 1; off < 256; off <<= 1) {
        int x = (t >= off) ? lstart[t - off] : 0;
        __syncthreads();
        lstart[t] += x;
        __syncthreads();
    }
    if (t < NBKT) {
        int v = hist[t];
        gstart[t] = atomicAdd(&bkt_pos[t], v);   // exact reservation, no padding
        lstart[t] -= v;                          // inclusive -> exclusive
        hist[t] = 0;                             // reuse as placement cursor
    }
    __syncthreads();
    // place records bucket-sorted into LDS: 8B record = {src | dl<<17, pack}
#pragma unroll
    for (int u = 0; u < ME_UNR; ++u) {
        int b = rb[u] >> 16, dl = rb[u] & 0xFFFF;
        int l = atomicAdd(&hist[b], 1);
        ((uint2*)recs)[lstart[b] + l] = make_uint2((uint)rs[u] | ((uint)dl << 17), rp[u]);
    }
    __syncthreads();
    // per-bucket wave-contiguous flush
    int w = t >> 6, lane = t & 63;
    uint2* gb2 = (uint2*)bkt;
    for (int b = w; b < NBKT; b += 4) {
        int n = hist[b];
        int ls = lstart[b];
        int gs = gstart[b];
        for (int off = lane; off < n; off += 64)
            if (gs + off < BKT_CAP)
                gb2[(size_t)b * BKT_CAP + gs + off] = ((const uint2*)recs)[ls + off];
    }
#pragma unroll
    for (int k = 0; k < 8; ++k) p[k] = waveReduceSum(p[k]);
    if ((t & 63) == 0) {
        float* dstp = partials + ((size_t)blockIdx.x * 4 + w) * 8;
#pragma unroll
        for (int k = 0; k < 8; ++k) dstp[k] = p[k];
    }
}

// ---------- K2b: merged finalize — mean finish + bucket-count scan ----------
__global__ __launch_bounds__(256) void k_finalize(const float* __restrict__ partials,
                                                  const float* __restrict__ we_vec,
                                                  const int* __restrict__ bkt_pos,
                                                  uint* __restrict__ ltp,
                                                  int* __restrict__ bktbase,
                                                  int* __restrict__ row_ptr) {
    __shared__ float red[256];
    __shared__ float mean8[8];
    __shared__ float lt[2];
    __shared__ int sd[256];
    int t = threadIdx.x;
    // phase 1: edge_attr mean -> loop terms (we_vec already log2e-scaled)
    int k = t & 7;
    int chunk = t >> 3;
    float s = 0.0f;
    for (int i = chunk; i < PART_CH; i += 32) s += partials[(size_t)i * 8 + k];
    red[t] = s;
    __syncthreads();
    if (t < 8) {
        float acc = 0.0f;
#pragma unroll
        for (int c = 0; c < 32; ++c) acc += red[c * 8 + t];
        mean8[t] = acc * (1.0f / N_EDGES);
    }
    __syncthreads();
    if (t < 2) {
        float acc = 0.0f;
#pragma unroll
        for (int kk = 0; kk < 8; ++kk) acc += mean8[kk] * we_vec[t * 8 + kk];
        lt[t] = acc;
    }
    __syncthreads();
    if (t == 0) ltp[0] = pack_bf2(lt[0], lt[1]);
    // phase 2: scan bucket counts -> bucket CSR bases
    int v = (t < NBKT) ? min(bkt_pos[t], BKT_CAP) + BKT_W : 0;
    sd[t] = v;
    __syncthreads();
    for (int off = 1; off < 256; off <<= 1) {
        int x = (t >= off) ? sd[t - off] : 0;
        __syncthreads();
        sd[t] += x;
        __syncthreads();
    }
    if (t < NBKT) bktbase[t] = sd[t] - v;
    if (t == 0) row_ptr[N_NODES] = E_SL;
}

// kB: one block per bucket. Counting-sort the bucket's ~6400 8B records in LDS,
// write row_ptr for its 400 nodes, write agg as fully contiguous stream.
__global__ __launch_bounds__(SB_THREADS) void k_sort_build(const int* __restrict__ bkt_pos,
                                                           const uint* __restrict__ bkt,
                                                           const int* __restrict__ bktbase,
                                                           const uint* __restrict__ ltp,
                                                           int2* __restrict__ agg,
                                                           int* __restrict__ row_ptr) {
    __shared__ int S[BKT_W];                 // inclusive scan of per-node counts
    __shared__ int cur[BKT_W];               // hist, then rank cursor
    __shared__ unsigned short sel[SEL_CAP];  // local position -> record idx | selfloop
    int b = blockIdx.x;
    int t = threadIdx.x;
    int cnt = min(bkt_pos[b], BKT_CAP);
    const uint2* bp = (const uint2*)bkt + (size_t)b * BKT_CAP;
    if (t < BKT_W) cur[t] = 0;
    __syncthreads();
    for (int i = t; i < cnt; i += SB_THREADS) {
        uint2 v = bp[i];                     // streams bucket through L2
        atomicAdd(&cur[v.x >> 17], 1);
    }
    __syncthreads();
    if (t < BKT_W) S[t] = cur[t];
    for (int off = 1; off < BKT_W; off <<= 1) {
        __syncthreads();
        int x = (t >= off && t < BKT_W) ? S[t - off] : 0;
        __syncthreads();
        if (t < BKT_W) S[t] += x;
    }
    __syncthreads();
    int n0 = b * BKT_W;
    int gb = bktbase[b];
    if (t < BKT_W) {
        row_ptr[n0 + t] = gb + (t == 0 ? 0 : S[t - 1]) + t;   // excl scan of (cnt+1)
        cur[t] = 0;
        sel[S[t] + t] = (unsigned short)(0x8000 | t);   // self-loop slot (segment end)
    }
    __syncthreads();
    for (int i = t; i < cnt; i += SB_THREADS) {
        int dl = (int)(bp[i].x >> 17);       // L2 re-read
        int r = atomicAdd(&cur[dl], 1);
        int nb = (dl == 0) ? 0 : S[dl - 1];
        sel[nb + dl + r] = (unsigned short)i;
    }
    __syncthreads();
    int total = cnt + BKT_W;
    uint lt = ltp[0];
    for (int p = t; p < total; p += SB_THREADS) {
        unsigned short v = sel[p];
        int2 a;
        if (v & 0x8000) {
            a = make_int2(n0 + (v & 0x7fff), (int)lt);
        } else {
            uint2 r = bp[v];                 // random read within resident bucket
            a = make_int2((int)(r.x & 0x1FFFFu), (int)r.y);
        }
        agg[gb + p] = a;                     // contiguous coalesced stream
    }
}

// ---------- K3: layer-0 projection xp = x@Wc + bc ----------
__global__ __launch_bounds__(256) void k_xp0(const float* __restrict__ x,
                                             const float* __restrict__ Wc,
                                             const float* __restrict__ bc,
                                             const float* __restrict__ a_src,
                                             const float* __restrict__ a_dst,
                                             __hip_bfloat16* __restrict__ xpb,
                                             float* __restrict__ s_src,
                                             float* __restrict__ s_dst) {
    __shared__ float xr[NPB * F_INN];  // 4 KB
    int t = threadIdx.x;
    int j = t & 63, wv = t >> 6;
    float4 w[F_INN / 4];               // 8 VGPR float4s = weight column j
#pragma unroll
    for (int kk = 0; kk < F_INN / 4; ++kk) {
        w[kk].x = Wc[(4 * kk + 0) * HD + j];
        w[kk].y = Wc[(4 * kk + 1) * HD + j];
        w[kk].z = Wc[(4 * kk + 2) * HD + j];
        w[kk].w = Wc[(4 * kk + 3) * HD + j];
    }
    int n0 = blockIdx.x * NPB;
    ((float4*)xr)[t] = ((const float4*)(x + (size_t)n0 * F_INN))[t];  // 4KB exact
    __syncthreads();
    float asj = a_src[j], adj = a_dst[j], bcj = bc[j];
    for (int n = wv; n < NPB; n += 4) {
        const float4* hx = (const float4*)&xr[n * F_INN];
        float acc = bcj;
#pragma unroll
        for (int kk = 0; kk < F_INN / 4; ++kk) {
            float4 hv = hx[kk];   // wave-uniform broadcast ds_read_b128
            acc += hv.x * w[kk].x + hv.y * w[kk].y + hv.z * w[kk].z + hv.w * w[kk].w;
        }
        int node = n0 + n;
        xpb[(size_t)node * HD + j] = __float2bfloat16(acc);
        float ts = waveReduceSum(acc * asj);
        float td = waveReduceSum(acc * adj);
        if (j == 0) { s_src[node] = ts * LOG2E; s_dst[node] = td * LOG2E; }   // exp2 rebase
    }
}

// ---------- K4: xp(bf16) = h @ W (layer 1) — h bf16 ----------
__global__ __launch_bounds__(256) void k_xp(const unsigned short* __restrict__ hb,
                                            const float* __restrict__ W,
                                            const float* __restrict__ a_src, const float* __restrict__ a_dst,
                                            __hip_bfloat16* __restrict__ xpb, float* __restrict__ s_src,
                                            float* __restrict__ s_dst) {
    __shared__ unsigned short hr[NPB * HD];   // 4 KB bf16 tile
    int t = threadIdx.x;
    int j = t & 63, wv = t >> 6;
    float4 w[HD / 4];                  // 16 float4s = 64 VGPRs
#pragma unroll
    for (int kk = 0; kk < HD / 4; ++kk) {
        w[kk].x = W[(4 * kk + 0) * HD + j];
        w[kk].y = W[(4 * kk + 1) * HD + j];
        w[kk].z = W[(4 * kk + 2) * HD + j];
        w[kk].w = W[(4 * kk + 3) * HD + j];
    }
    int n0 = blockIdx.x * NPB;
    ((uint4*)hr)[t] = ((const uint4*)(hb + (size_t)n0 * HD))[t];   // 4KB exact
    __syncthreads();
    float asj = a_src[j], adj = a_dst[j];
    for (int n = wv; n < NPB; n += 4) {
        const uint2* hx = (const uint2*)&hr[n * HD];
        float acc = 0.0f;
#pragma unroll
        for (int kk = 0; kk < HD / 4; ++kk) {
            uint2 hv = hx[kk];   // broadcast ds_read_b64: 4 bf16
            acc += bf_lo(hv.x) * w[kk].x + bf_hi(hv.x) * w[kk].y
                 + bf_lo(hv.y) * w[kk].z + bf_hi(hv.y) * w[kk].w;
        }
        int node = n0 + n;
        xpb[(size_t)node * HD + j] = __float2bfloat16(acc);
        float ts = waveReduceSum(acc * asj);
        float td = waveReduceSum(acc * adj);
        if (j == 0) { s_src[node] = ts * LOG2E; s_dst[node] = td * LOG2E; }   // exp2 rebase
    }
}

// ---------- K5: gather-aggregate — REVERTED to the r9 structure (best
// measured: 54.1 µs) after r11's deeper pipeline regressed it (56.2 µs,
// VGPR 20->24, VALU 67->71%: TLP at ~71% occupancy already covers gather
// latency; extra in-flight state only added issue overhead). Only surviving
// r11 change: exp2 rebase — one v_mul per edge-visit deleted, exp2f lowers
// to the native v_exp_f32. Record-only 1-deep prefetch, flattened 8-wide
// predicated tail, 32-bit gather offsets. ----------
template <int LAYER>
__global__ __launch_bounds__(256) void k_aggregate(const int* __restrict__ row_ptr,
                                                   const int2* __restrict__ agg,
                                                   const float* __restrict__ s_src,
                                                   const float* __restrict__ s_dst,
                                                   const uint2* __restrict__ xpr,   // bf16 x4 per lane
                                                   const float* __restrict__ bias,
                                                   unsigned short* __restrict__ hb) {
    int t = threadIdx.x;
    int node = blockIdx.x * 4 + (t >> 6);    // grid exact: N/4
    int lane = t & 63;
    int g = lane >> 4, li = lane & 15;
    int start = row_ptr[node], end = row_ptr[node + 1];
    float sd = s_dst[node];
    float ax = 0.0f, ay = 0.0f, az = 0.0f, aw = 0.0f, den = 0.0f;
    int i = start;
    if (i + 8 <= end) {
        int2 r0 = agg[i + g];
        int2 r1 = agg[i + 4 + g];
        while (true) {
            int ni = i + 8;
            bool more = ni + 8 <= end;
            int2 nr0, nr1;
            if (more) { nr0 = agg[ni + g]; nr1 = agg[ni + 4 + g]; }   // prefetch next records
            int sp0 = r0.x, sp1 = r1.x;
            uint2 u0 = xpr[(uint)(sp0 * 16 + li)];
            uint2 u1 = xpr[(uint)(sp1 * 16 + li)];
            float a0 = s_src[sp0] + sd + (LAYER == 0 ? bf_lo((uint)r0.y) : bf_hi((uint)r0.y));
            float a1 = s_src[sp1] + sd + (LAYER == 0 ? bf_lo((uint)r1.y) : bf_hi((uint)r1.y));
            a0 = a0 > 0.0f ? a0 : NEG_SLOPE * a0;
            a1 = a1 > 0.0f ? a1 : NEG_SLOPE * a1;
            float ex0 = exp2f(a0), ex1 = exp2f(a1);
            den += ex0 + ex1;
            ax += ex0 * bf_lo(u0.x) + ex1 * bf_lo(u1.x);
            ay += ex0 * bf_hi(u0.x) + ex1 * bf_hi(u1.x);
            az += ex0 * bf_lo(u0.y) + ex1 * bf_lo(u1.y);
            aw += ex0 * bf_hi(u0.y) + ex1 * bf_hi(u1.y);
            i = ni;
            if (!more) break;
            r0 = nr0; r1 = nr1;
        }
    }
    if (i < end) {                           // single predicated 8-wide tail pass
        int idx0 = i + g, idx1 = i + 4 + g;
        bool v0 = idx0 < end, v1 = idx1 < end;
        int2 r0 = agg[v0 ? idx0 : start];
        int2 r1 = agg[v1 ? idx1 : start];
        int sp0 = r0.x, sp1 = r1.x;
        uint2 u0 = xpr[(uint)(sp0 * 16 + li)];
        uint2 u1 = xpr[(uint)(sp1 * 16 + li)];
        float a0 = s_src[sp0] + sd + (LAYER == 0 ? bf_lo((uint)r0.y) : bf_hi((uint)r0.y));
        float a1 = s_src[sp1] + sd + (LAYER == 0 ? bf_lo((uint)r1.y) : bf_hi((uint)r1.y));
        a0 = a0 > 0.0f ? a0 : NEG_SLOPE * a0;
        a1 = a1 > 0.0f ? a1 : NEG_SLOPE * a1;
        float ex0 = v0 ? exp2f(a0) : 0.0f;
        float ex1 = v1 ? exp2f(a1) : 0.0f;
        den += ex0 + ex1;
        ax += ex0 * bf_lo(u0.x) + ex1 * bf_lo(u1.x);
        ay += ex0 * bf_hi(u0.x) + ex1 * bf_hi(u1.x);
        az += ex0 * bf_lo(u0.y) + ex1 * bf_lo(u1.y);
        aw += ex0 * bf_hi(u0.y) + ex1 * bf_hi(u1.y);
    }
    den += __shfl_down(den, 32, 64); ax += __shfl_down(ax, 32, 64);
    ay  += __shfl_down(ay, 32, 64); az += __shfl_down(az, 32, 64);
    aw  += __shfl_down(aw, 32, 64);
    den += __shfl_down(den, 16, 64); ax += __shfl_down(ax, 16, 64);
    ay  += __shfl_down(ay, 16, 64); az += __shfl_down(az, 16, 64);
    aw  += __shfl_down(aw, 16, 64);
    if (lane < 16) {
        float inv = 1.0f / (den + 1e-16f);
        float4 b4 = ((const float4*)bias)[li];
        uint2 hv;
        hv.x = pack_bf2(fmaxf(ax * inv + b4.x, 0.0f), fmaxf(ay * inv + b4.y, 0.0f));
        hv.y = pack_bf2(fmaxf(az * inv + b4.z, 0.0f), fmaxf(aw * inv + b4.w, 0.0f));
        ((uint2*)(hb + (size_t)node * HD))[li] = hv;
    }
}

// ---------- K6: u1(bf16)=h@W1a, u2b(bf16)=h@W1b + b1 — h bf16 ----------
__global__ __launch_bounds__(256) void k_umm(const unsigned short* __restrict__ hb,
                                             const float* __restrict__ w1,
                                             const float* __restrict__ b1,
                                             __hip_bfloat16* __restrict__ u1b,
                                             __hip_bfloat16* __restrict__ u2b) {
    __shared__ unsigned short hr[NPB * HD];   // 4 KB bf16 tile
    int t = threadIdx.x;
    int j = t & 63, wv = t >> 6;
    float4 wa[HD / 4], wb[HD / 4];     // 128 VGPRs
#pragma unroll
    for (int kk = 0; kk < HD / 4; ++kk) {
        wa[kk].x = w1[(4 * kk + 0) * HD + j];
        wa[kk].y = w1[(4 * kk + 1) * HD + j];
        wa[kk].z = w1[(4 * kk + 2) * HD + j];
        wa[kk].w = w1[(4 * kk + 3) * HD + j];
        wb[kk].x = w1[(HD + 4 * kk + 0) * HD + j];
        wb[kk].y = w1[(HD + 4 * kk + 1) * HD + j];
        wb[kk].z = w1[(HD + 4 * kk + 2) * HD + j];
        wb[kk].w = w1[(HD + 4 * kk + 3) * HD + j];
    }
    float b1j = b1[j];
    int n0 = blockIdx.x * NPB;
    ((uint4*)hr)[t] = ((const uint4*)(hb + (size_t)n0 * HD))[t];   // 4KB exact
    __syncthreads();
    for (int n = wv; n < NPB; n += 4) {
        const uint2* hx = (const uint2*)&hr[n * HD];
        float a1 = 0.0f, a2 = 0.0f;
#pragma unroll
        for (int kk = 0; kk < HD / 4; ++kk) {
            uint2 hv = hx[kk];   // broadcast ds_read_b64: 4 bf16
            float h0 = bf_lo(hv.x), h1 = bf_hi(hv.x), h2 = bf_lo(hv.y), h3 = bf_hi(hv.y);
            a1 += h0 * wa[kk].x + h1 * wa[kk].y + h2 * wa[kk].z + h3 * wa[kk].w;
            a2 += h0 * wb[kk].x + h1 * wb[kk].y + h2 * wb[kk].z + h3 * wb[kk].w;
        }
        int node = n0 + n;
        u1b[(size_t)node * HD + j] = __float2bfloat16(a1);
        u2b[(size_t)node * HD + j] = __float2bfloat16(a2 + b1j);
    }
}

// ---------- K7: edge-order decode — 128 edges/block, 8 per 16-lane group =
// 16 independent 128B row-gathers in flight per group. out coalesced. ----------
__global__ __launch_bounds__(256) void k_decode_edge(const int* __restrict__ src,
                                                     const int* __restrict__ dst,
                                                     const uint2* __restrict__ u1r,
                                                     const uint2* __restrict__ u2r,
                                                     const float* __restrict__ w2,
                                                     const float* __restrict__ b2,
                                                     float* __restrict__ out) {
    __shared__ int sld[2 * DEC_EPB];
    int t = threadIdx.x;
    int e0 = blockIdx.x * DEC_EPB;       // grid exact: E/128 blocks
    sld[t] = (t < DEC_EPB) ? src[e0 + t] : dst[e0 + t - DEC_EPB];
    __syncthreads();
    int g = t >> 4, li = t & 15;         // 16 groups of 16 lanes, 8 edges/group
    float4 w4 = ((const float4*)w2)[li];
    float bb = b2[0];
    uint2 u[8], v[8];
#pragma unroll
    for (int k = 0; k < 8; ++k) {        // 16 independent row gathers back-to-back
        int sk = sld[g + 16 * k];
        int dk = sld[DEC_EPB + g + 16 * k];
        u[k] = u1r[(uint)(sk * 16 + li)];
        v[k] = u2r[(uint)(dk * 16 + li)];
    }
    float p[8];
#pragma unroll
    for (int k = 0; k < 8; ++k) {
        p[k] = fmaxf(bf_lo(u[k].x) + bf_lo(v[k].x), 0.0f) * w4.x
             + fmaxf(bf_hi(u[k].x) + bf_hi(v[k].x), 0.0f) * w4.y
             + fmaxf(bf_lo(u[k].y) + bf_lo(v[k].y), 0.0f) * w4.z
             + fmaxf(bf_hi(u[k].y) + bf_hi(v[k].y), 0.0f) * w4.w;
    }
#pragma unroll
    for (int off = 8; off > 0; off >>= 1) {
#pragma unroll
        for (int k = 0; k < 8; ++k) p[k] += __shfl_down(p[k], off, 16);
    }
    if (li == 0) {
#pragma unroll
        for (int k = 0; k < 8; ++k)
            out[e0 + 16 * k + g] = 1.0f / (1.0f + __expf(-(p[k] + bb)));
    }
}

extern "C" void kernel_launch(void* const* d_in, const int* in_sizes, int n_in,
                              void* d_out, int out_size, void* d_ws, size_t ws_size,
                              hipStream_t stream) {
    const float* x        = (const float*)d_in[0];
    const int*   eidx     = (const int*)d_in[1];
    const float* eattr    = (const float*)d_in[2];
    const float* enc_w    = (const float*)d_in[3];
    const float* enc_b    = (const float*)d_in[4];
    const float* gat_w    = (const float*)d_in[5];
    const float* att_src  = (const float*)d_in[6];
    const float* att_dst  = (const float*)d_in[7];
    const float* edge_w   = (const float*)d_in[8];
    const float* att_edge = (const float*)d_in[9];
    const float* gat_b    = (const float*)d_in[10];
    const float* lp_w1    = (const float*)d_in[11];
    const float* lp_b1    = (const float*)d_in[12];
    const float* lp_w2    = (const float*)d_in[13];
    const float* lp_b2    = (const float*)d_in[14];
    float* out = (float*)d_out;

    const int* src = eidx;
    const int* dst = eidx + N_EDGES;

    // ---- workspace layout (bytes) ----
    // [0, 14.4MB):  bkt (8B records; live edterm->sort_build)
    //               hb bf16 N*HD = 12.8MB (live aggregate<0> -> umm) aliases it
    // [14.4, 27.2): xpb bf16 N*HD (u1b after umm)
    // [27.2, 40.8): agg E_SL int2 (u2b bf16 after umm — agg dead post agg<1>)
    // [40.8, ...):  small arrays
    char* wsb = (char*)d_ws;
    uint*   bkt = (uint*)wsb;                               // NBKT*BKT_CAP*8B = 14.4MB
    unsigned short* hb = (unsigned short*)wsb;              // N*HD bf16 (12.8MB)
    __hip_bfloat16* xpb = (__hip_bfloat16*)(wsb + (size_t)NBKT * BKT_CAP * 8);
    int2*   agg = (int2*)((char*)xpb + (size_t)N_NODES * HD * 2);   // 13.6MB
    float*  fsmall    = (float*)(agg + E_SL);
    float*  s_src     = fsmall;                             // N
    float*  s_dst     = s_src + N_NODES;                    // N
    float*  partials  = s_dst + N_NODES;                    // PART_CH*8 (20000)
    float*  we_vec    = partials + PART_CH * 8;             // 16
    uint*   ltp       = (uint*)(we_vec + 16);               // 1
    float*  Wc        = (float*)(ltp + 1);                  // 32*64
    float*  bc        = Wc + F_INN * HD;                    // 64
    int*    row_ptr   = (int*)(bc + HD);                    // N+1
    int*    bkt_pos   = row_ptr + N_NODES + 1;              // NBKT
    int*    bktbase   = bkt_pos + NBKT;                     // NBKT

    const int NB_AGG  = N_NODES / 4;             // 25000
    const int NB_DENSE = N_NODES / NPB;          // 3125
    const int NB_DEC  = N_EDGES / DEC_EPB;       // 12500

    // merged setup (we_vec + Wc/bc + counter zero) then fused edge pass
    k_setup<<<1, 256, 0, stream>>>(edge_w, att_edge, enc_w, enc_b, gat_w,
                                   we_vec, Wc, bc, bkt_pos);
    k_mean_edterm<<<ME_BLOCKS, 256, 0, stream>>>(eattr, src, dst, we_vec,
                                                 partials, bkt, bkt_pos);
    k_finalize<<<1, 256, 0, stream>>>(partials, we_vec, bkt_pos, ltp, bktbase, row_ptr);

    // per-bucket LDS counting sort -> CSR agg records + row_ptr
    k_sort_build<<<NBKT, SB_THREADS, 0, stream>>>(bkt_pos, bkt, bktbase, ltp,
                                                  agg, row_ptr);

    // layer-0 projection (encoder folded into Wc/bc)
    k_xp0<<<NB_DENSE, 256, 0, stream>>>(x, Wc, bc, att_src, att_dst, xpb, s_src, s_dst);
    k_aggregate<0><<<NB_AGG, 256, 0, stream>>>(row_ptr, agg, s_src, s_dst,
                                               (const uint2*)xpb, gat_b, hb);
    // GAT layer 1
    k_xp<<<NB_DENSE, 256, 0, stream>>>(hb, gat_w + HD * HD, att_src + HD, att_dst + HD,
                                       xpb, s_src, s_dst);
    k_aggregate<1><<<NB_AGG, 256, 0, stream>>>(row_ptr, agg, s_src, s_dst,
                                               (const uint2*)xpb, gat_b + HD, hb);

    // decoder: u1b -> xpb buffer, u2b(+b1) -> agg buffer (both dead by now);
    // decode in ORIGINAL edge order (coalesced out)
    k_umm<<<NB_DENSE, 256, 0, stream>>>(hb, lp_w1, lp_b1, xpb,
                                        (__hip_bfloat16*)agg);
    k_decode_edge<<<NB_DEC, 256, 0, stream>>>(src, dst, (const uint2*)xpb,
                                              (const uint2*)agg, lp_w2, lp_b2, out);
}